// Round 4
// baseline (158.856 us; speedup 1.0000x reference)
//
#include <hip/hip_runtime.h>

// Problem constants (B=4, S=2048, H=1024, E=8)
#define H 1024
#define E 8
#define T 8192          // B*S
#define CAP 1024        // T/E, capacity_factor=1.0 top-1

typedef __bf16 bf16x8 __attribute__((ext_vector_type(8)));
typedef float  f32x4  __attribute__((ext_vector_type(4)));
typedef unsigned short u16;

// round-to-nearest-even f32 -> bf16 bits
__device__ __forceinline__ u16 f2bf(float f) {
    union { float f; unsigned u; } v; v.f = f;
    unsigned r = v.u + 0x7FFFu + ((v.u >> 16) & 1u);
    return (u16)(r >> 16);
}

// async global->LDS, 16 B per lane
typedef __attribute__((address_space(1))) const void* gas_t;
typedef __attribute__((address_space(3))) void* las_t;
__device__ __forceinline__ void gld16(const void* g, void* l) {
    __builtin_amdgcn_global_load_lds((gas_t)g, (las_t)l, 16, 0, 0);
}

// ---------------------------------------------------------------------------
// Kernel 1: fused gate + x->bf16 (blocks [0,512)) and W->bf16 (blocks
// [512,2048), grid-stride). Gate math identical to prior passing versions.
// ---------------------------------------------------------------------------
#define GATE_BLOCKS 512
#define CVT_BLOCKS  1536

__global__ __launch_bounds__(256) void gatecvt_kernel(
    const float* __restrict__ x, const float* __restrict__ wg,
    const float* __restrict__ W,
    int* __restrict__ eid, float* __restrict__ gate,
    u16* __restrict__ xbf, u16* __restrict__ Wbf) {
    const int tid = threadIdx.x;

    if (blockIdx.x >= GATE_BLOCKS) {       // ---- W fp32 -> bf16 ----
        int i = (blockIdx.x - GATE_BLOCKS) * 256 + tid;
        const int n4 = E * H * H / 4;
        const int stride = CVT_BLOCKS * 256;
        for (; i < n4; i += stride) {
            float4 v = ((const float4*)W)[i];
            ushort4 o;
            o.x = f2bf(v.x); o.y = f2bf(v.y); o.z = f2bf(v.z); o.w = f2bf(v.w);
            ((ushort4*)Wbf)[i] = o;
        }
        return;
    }

    // ---- gating, 16 tokens/block (4/wave) ----
    const int wv = tid >> 6, lane = tid & 63;
    const int tbase = blockIdx.x * 16 + wv * 4;
    const int h00 = lane * 4;

    float a[4][8];
    #pragma unroll
    for (int j = 0; j < 4; ++j)
        #pragma unroll
        for (int e = 0; e < 8; ++e) a[j][e] = 0.f;

    #pragma unroll
    for (int q = 0; q < 4; ++q) {
        const int h0 = q * 256 + h00;
        float4 xv[4];
        #pragma unroll
        for (int j = 0; j < 4; ++j)
            xv[j] = *(const float4*)(x + (size_t)(tbase + j) * H + h0);
        #pragma unroll
        for (int j = 0; j < 4; ++j) {
            ushort4 o;
            o.x = f2bf(xv[j].x); o.y = f2bf(xv[j].y);
            o.z = f2bf(xv[j].z); o.w = f2bf(xv[j].w);
            *(ushort4*)(xbf + (size_t)(tbase + j) * H + h0) = o;
        }
        float wr[4][8];
        #pragma unroll
        for (int r = 0; r < 4; ++r) {
            const float4* p = (const float4*)(wg + (size_t)(h0 + r) * E);
            float4 lo = p[0], hi = p[1];
            wr[r][0] = lo.x; wr[r][1] = lo.y; wr[r][2] = lo.z; wr[r][3] = lo.w;
            wr[r][4] = hi.x; wr[r][5] = hi.y; wr[r][6] = hi.z; wr[r][7] = hi.w;
        }
        #pragma unroll
        for (int e = 0; e < 8; ++e)
            #pragma unroll
            for (int j = 0; j < 4; ++j)
                a[j][e] += xv[j].x * wr[0][e] + xv[j].y * wr[1][e]
                         + xv[j].z * wr[2][e] + xv[j].w * wr[3][e];
    }

    const bool b0 = lane & 1, b1 = lane & 2, b2 = lane & 4;
    const int elane = ((lane & 1) << 2) | (lane & 2) | ((lane >> 2) & 1);

    #pragma unroll
    for (int j = 0; j < 4; ++j) {
        float* A = a[j];
        #pragma unroll
        for (int k = 0; k < 4; ++k) {
            float t = b0 ? A[k] : A[k + 4];
            t = __shfl_xor(t, 1);
            A[k] = (b0 ? A[k + 4] : A[k]) + t;
        }
        #pragma unroll
        for (int k = 0; k < 2; ++k) {
            float t = b1 ? A[k] : A[k + 2];
            t = __shfl_xor(t, 2);
            A[k] = (b1 ? A[k + 2] : A[k]) + t;
        }
        {
            float t = b2 ? A[0] : A[1];
            t = __shfl_xor(t, 4);
            A[0] = (b2 ? A[1] : A[0]) + t;
        }
        float v = A[0];
        v += __shfl_xor(v, 8); v += __shfl_xor(v, 16); v += __shfl_xor(v, 32);
        float m = v; int mi = elane;
        #pragma unroll
        for (int off = 1; off <= 4; off <<= 1) {
            float om = __shfl_xor(m, off);
            int   oi = __shfl_xor(mi, off);
            if (om > m || (om == m && oi < mi)) { m = om; mi = oi; }
        }
        float s = expf(v - m);
        s += __shfl_xor(s, 1); s += __shfl_xor(s, 2); s += __shfl_xor(s, 4);
        if (lane == 0) {
            eid[tbase + j]  = mi;
            gate[tbase + j] = 1.0f / s;
        }
    }
}

// ---------------------------------------------------------------------------
// Kernel 2: capacity scan, 1024 threads, serial depth 8.
// ---------------------------------------------------------------------------
#define SCAN_T 1024
#define STPT 8
__global__ __launch_bounds__(1024) void scan_kernel(
    const int* __restrict__ eid, float* __restrict__ gate,
    int* __restrict__ perm) {
    __shared__ int cnt[SCAN_T][E];     // 32 KB
    __shared__ int part[E][32];
    const int tid = threadIdx.x;

    for (int i = tid; i < E * CAP; i += SCAN_T) perm[i] = -1;

    const int t0 = tid * STPT;
    int ei[STPT];
    #pragma unroll
    for (int i = 0; i < STPT; ++i) ei[i] = eid[t0 + i];

    int c[E];
    #pragma unroll
    for (int e = 0; e < E; ++e) c[e] = 0;
    #pragma unroll
    for (int i = 0; i < STPT; ++i)
        #pragma unroll
        for (int e = 0; e < E; ++e) c[e] += (ei[i] == e);
    #pragma unroll
    for (int e = 0; e < E; ++e) cnt[tid][e] = c[e];
    __syncthreads();

    if (tid < 256) {                       // 8 experts x 32 groups of 32
        const int e = tid >> 5, g = tid & 31;
        int s = 0;
        for (int i = g * 32; i < g * 32 + 32; ++i) s += cnt[i][e];
        part[e][g] = s;
    }
    __syncthreads();
    if (tid < E) {
        int run = 0;
        #pragma unroll
        for (int g = 0; g < 32; ++g) { int v = part[tid][g]; part[tid][g] = run; run += v; }
    }
    __syncthreads();
    if (tid < 256) {                       // scatter exclusive bases back into cnt
        const int e = tid >> 5, g = tid & 31;
        int run = part[e][g];
        for (int i = g * 32; i < g * 32 + 32; ++i) { int v = cnt[i][e]; cnt[i][e] = run; run += v; }
    }
    __syncthreads();

    #pragma unroll
    for (int e = 0; e < E; ++e) c[e] = cnt[tid][e];
    #pragma unroll
    for (int i = 0; i < STPT; ++i) {
        const int t = t0 + i, e0 = ei[i];
        int pos = 0;
        #pragma unroll
        for (int k = 0; k < E; ++k) if (e0 == k) pos = c[k]++;
        if (pos < CAP) perm[e0 * CAP + pos] = t;
        else gate[t] = 0.f;               // dropped; kept tokens have gate >= 1/8
    }
}

// ---------------------------------------------------------------------------
// Kernel 3: gathered GEMM, BM=256 x BN=128, BK=64, depth-3 ring, ONE barrier
// per K-step: STAGE(t+2) is issued at the TOP of compute(t) (loads overlap
// MFMAs), then a single counted s_waitcnt vmcnt(6) + s_barrier per step.
// WAR: stage target buf[(cur+2)%3] was last read at step t-1, separated by
// the end-of-(t-1) barrier. Drain: after compute(t), outstanding = tile t+2's
// 6 loads; vmcnt(6) guarantees tile t+1 complete. Tail: vmcnt(0) at t=14.
// Blocks [0,64): zero-dropped-rows plane (LDS-free; co-resides with GEMM).
// ---------------------------------------------------------------------------
__global__ __launch_bounds__(512, 2) void moe_gemm_bf(
    const u16* __restrict__ xbf, const u16* __restrict__ Wbf,
    const float* __restrict__ bias, const int* __restrict__ perm,
    const float* __restrict__ gate, float* __restrict__ out) {
    __shared__ __align__(16) u16 As[3][256 * 64];   // 3 x 32 KB
    __shared__ __align__(16) u16 Bs[3][128 * 64];   // 3 x 16 KB
    __shared__ int   perm_s[256];
    __shared__ float gate_s[256];

    const int tid = threadIdx.x;
    const int bid = blockIdx.x;

    if (bid < 64) {                 // ---- zero rows of dropped tokens ----
        const int t = bid * 128 + (tid >> 2);
        if (gate[t] == 0.f) {
            const int part = tid & 3;
            float4 z = make_float4(0.f, 0.f, 0.f, 0.f);
            float4* o = (float4*)(out + (size_t)t * H + part * 256);
            #pragma unroll
            for (int i = 0; i < 64; ++i) o[i] = z;
        }
        return;
    }

    const int idx = bid - 64;
    const int e  = idx & 7;           // expert -> XCD (round-robin heuristic)
    const int mb = (idx >> 3) & 3;    // slot block (256 slots)
    const int fb = idx >> 5;          // feature block (128 features)

    if (tid < 256) {
        const int t = perm[e * CAP + mb * 256 + tid];
        perm_s[tid] = t;
        gate_s[tid] = (t >= 0) ? gate[t] : 0.f;
    }
    __syncthreads();

    const int lane = tid & 63;
    const int wv = tid >> 6;          // 0..7
    const int wm2 = wv >> 1;          // 0..3 : 64-row M block
    const int wn2 = wv & 1;           // 0..1 : 64-col N block
    const int l16 = lane & 15, quad = lane >> 4;

    // staging: per round, wave wv covers 8 rows (rl = lane>>3), 8 chunks of
    // 16B per row. LDS[row][c] = G[row][c ^ (row&7)], achieved by
    // pre-swizzling the global chunk: gch = cch ^ rl (row&7 == rl).
    const int rl  = lane >> 3;
    const int cch = lane & 7;
    const int gch = cch ^ rl;

    const u16* ga[4];                 // A: 4 rounds x 64 rows = 256 rows
    #pragma unroll
    for (int q = 0; q < 4; ++q) {
        const int r = q * 64 + wv * 8 + rl;
        const int tA = perm_s[r];
        const int tok = tA >= 0 ? tA : 0;
        ga[q] = xbf + (size_t)tok * H + gch * 8;
    }
    const u16* gb[2];                 // B: 2 rounds x 64 rows = 128 rows
    #pragma unroll
    for (int q = 0; q < 2; ++q) {
        const int r = fb * 128 + q * 64 + wv * 8 + rl;
        gb[q] = Wbf + (size_t)e * H * H + (size_t)r * H + gch * 8;
    }

#define STAGE(BUF, TT)                                                        \
    {                                                                         \
        _Pragma("unroll")                                                     \
        for (int q = 0; q < 4; ++q)                                           \
            gld16(ga[q] + (TT) * 64, &As[BUF][(q * 64 + wv * 8) * 64 + lane * 8]); \
        _Pragma("unroll")                                                     \
        for (int q = 0; q < 2; ++q)                                           \
            gld16(gb[q] + (TT) * 64, &Bs[BUF][(q * 64 + wv * 8) * 64 + lane * 8]); \
    }

    f32x4 acc[4][4] = {};

    // prologue: stage tiles 0,1 (12 loads); wait tile 0 (tile 1 in flight)
    STAGE(0, 0)
    STAGE(1, 1)
    asm volatile("s_waitcnt vmcnt(6)" ::: "memory");
    __builtin_amdgcn_sched_barrier(0);
    __builtin_amdgcn_s_barrier();
    __builtin_amdgcn_sched_barrier(0);

    int cur = 0;
    #pragma unroll 1
    for (int t = 0; t < 16; ++t) {
        int nx2 = cur + 2; if (nx2 >= 3) nx2 -= 3;
        if (t < 14) STAGE(nx2, t + 2)       // overlaps with this step's MFMAs

        const u16* cA = As[cur];
        const u16* cB = Bs[cur];
        #pragma unroll
        for (int kh = 0; kh < 2; ++kh) {
            bf16x8 af[4], bf[4];
            const int cc = (kh * 4 + quad) ^ (l16 & 7);
            #pragma unroll
            for (int mi = 0; mi < 4; ++mi)
                af[mi] = *(const bf16x8*)&cA[(wm2 * 64 + mi * 16 + l16) * 64 + cc * 8];
            #pragma unroll
            for (int ni = 0; ni < 4; ++ni)
                bf[ni] = *(const bf16x8*)&cB[(wn2 * 64 + ni * 16 + l16) * 64 + cc * 8];
            #pragma unroll
            for (int mi = 0; mi < 4; ++mi)
                #pragma unroll
                for (int ni = 0; ni < 4; ++ni)
                    acc[mi][ni] = __builtin_amdgcn_mfma_f32_16x16x32_bf16(
                        af[mi], bf[ni], acc[mi][ni], 0, 0, 0);
        }
        if (t == 15) break;

        __builtin_amdgcn_sched_barrier(0);
        if (t < 14) asm volatile("s_waitcnt vmcnt(6)" ::: "memory");
        else        asm volatile("s_waitcnt vmcnt(0)" ::: "memory");
        __builtin_amdgcn_sched_barrier(0);
        __builtin_amdgcn_s_barrier();       // single barrier per K-step
        __builtin_amdgcn_sched_barrier(0);
        cur = (cur == 2) ? 0 : cur + 1;
    }
#undef STAGE

    // epilogue: C/D layout col=lane&15, row=quad*4+reg
    float bv[4];
    #pragma unroll
    for (int ni = 0; ni < 4; ++ni)
        bv[ni] = bias[e * H + fb * 128 + wn2 * 64 + ni * 16 + l16];

    #pragma unroll
    for (int mi = 0; mi < 4; ++mi) {
        #pragma unroll
        for (int r = 0; r < 4; ++r) {
            const int rowl = wm2 * 64 + mi * 16 + quad * 4 + r;
            const int t = perm_s[rowl];
            if (t < 0) continue;
            const float g = gate_s[rowl];
            float* orow = out + (size_t)t * H + fb * 128 + wn2 * 64;
            #pragma unroll
            for (int ni = 0; ni < 4; ++ni)
                orow[ni * 16 + l16] = g * (acc[mi][ni][r] + bv[ni]);
        }
    }
}

extern "C" void kernel_launch(void* const* d_in, const int* in_sizes, int n_in,
                              void* d_out, int out_size, void* d_ws, size_t ws_size,
                              hipStream_t stream) {
    const float* x    = (const float*)d_in[0];  // [T,H]
    const float* wg   = (const float*)d_in[1];  // [H,E]
    const float* W    = (const float*)d_in[2];  // [E,H,H]
    const float* bias = (const float*)d_in[3];  // [E,H]
    float* out = (float*)d_out;

    // ws: eid[T] | gate[T] | perm[E*CAP] | xbf[T*H] bf16 | Wbf[E*H*H] bf16
    int*   eid  = (int*)d_ws;
    float* gate = (float*)((char*)d_ws + (size_t)T * 4);
    int*   perm = (int*)((char*)d_ws + (size_t)T * 8);
    u16*   xbf  = (u16*)((char*)d_ws + (size_t)T * 12);
    u16*   Wbf  = xbf + (size_t)T * H;

    gatecvt_kernel<<<GATE_BLOCKS + CVT_BLOCKS, 256, 0, stream>>>(
        x, wg, W, eid, gate, xbf, Wbf);
    scan_kernel<<<1, SCAN_T, 0, stream>>>(eid, gate, perm);
    moe_gemm_bf<<<64 + 256, 512, 0, stream>>>(xbf, Wbf, bias, perm, gate, out);
}

// Round 5
// 156.039 us; speedup vs baseline: 1.0181x; 1.0181x over previous
//
#include <hip/hip_runtime.h>

// Problem constants (B=4, S=2048, H=1024, E=8)
#define H 1024
#define E 8
#define T 8192          // B*S
#define CAP 1024        // T/E, capacity_factor=1.0 top-1

typedef __bf16 bf16x8 __attribute__((ext_vector_type(8)));
typedef float  f32x4  __attribute__((ext_vector_type(4)));
typedef unsigned short u16;

// round-to-nearest-even f32 -> bf16 bits
__device__ __forceinline__ u16 f2bf(float f) {
    union { float f; unsigned u; } v; v.f = f;
    unsigned r = v.u + 0x7FFFu + ((v.u >> 16) & 1u);
    return (u16)(r >> 16);
}

// async global->LDS, 16 B per lane
typedef __attribute__((address_space(1))) const void* gas_t;
typedef __attribute__((address_space(3))) void* las_t;
__device__ __forceinline__ void gld16(const void* g, void* l) {
    __builtin_amdgcn_global_load_lds((gas_t)g, (las_t)l, 16, 0, 0);
}

// ---------------------------------------------------------------------------
// Kernel 1: fused gate + x->bf16 (blocks [0,512)) and W->bf16 (blocks
// [512,2048), grid-stride). Gate math identical to prior passing versions.
// ---------------------------------------------------------------------------
#define GATE_BLOCKS 512
#define CVT_BLOCKS  1536

__global__ __launch_bounds__(256) void gatecvt_kernel(
    const float* __restrict__ x, const float* __restrict__ wg,
    const float* __restrict__ W,
    int* __restrict__ eid, float* __restrict__ gate,
    u16* __restrict__ xbf, u16* __restrict__ Wbf) {
    const int tid = threadIdx.x;

    if (blockIdx.x >= GATE_BLOCKS) {       // ---- W fp32 -> bf16 ----
        int i = (blockIdx.x - GATE_BLOCKS) * 256 + tid;
        const int n4 = E * H * H / 4;
        const int stride = CVT_BLOCKS * 256;
        for (; i < n4; i += stride) {
            float4 v = ((const float4*)W)[i];
            ushort4 o;
            o.x = f2bf(v.x); o.y = f2bf(v.y); o.z = f2bf(v.z); o.w = f2bf(v.w);
            ((ushort4*)Wbf)[i] = o;
        }
        return;
    }

    // ---- gating, 16 tokens/block (4/wave) ----
    const int wv = tid >> 6, lane = tid & 63;
    const int tbase = blockIdx.x * 16 + wv * 4;
    const int h00 = lane * 4;

    float a[4][8];
    #pragma unroll
    for (int j = 0; j < 4; ++j)
        #pragma unroll
        for (int e = 0; e < 8; ++e) a[j][e] = 0.f;

    #pragma unroll
    for (int q = 0; q < 4; ++q) {
        const int h0 = q * 256 + h00;
        float4 xv[4];
        #pragma unroll
        for (int j = 0; j < 4; ++j)
            xv[j] = *(const float4*)(x + (size_t)(tbase + j) * H + h0);
        #pragma unroll
        for (int j = 0; j < 4; ++j) {
            ushort4 o;
            o.x = f2bf(xv[j].x); o.y = f2bf(xv[j].y);
            o.z = f2bf(xv[j].z); o.w = f2bf(xv[j].w);
            *(ushort4*)(xbf + (size_t)(tbase + j) * H + h0) = o;
        }
        float wr[4][8];
        #pragma unroll
        for (int r = 0; r < 4; ++r) {
            const float4* p = (const float4*)(wg + (size_t)(h0 + r) * E);
            float4 lo = p[0], hi = p[1];
            wr[r][0] = lo.x; wr[r][1] = lo.y; wr[r][2] = lo.z; wr[r][3] = lo.w;
            wr[r][4] = hi.x; wr[r][5] = hi.y; wr[r][6] = hi.z; wr[r][7] = hi.w;
        }
        #pragma unroll
        for (int e = 0; e < 8; ++e)
            #pragma unroll
            for (int j = 0; j < 4; ++j)
                a[j][e] += xv[j].x * wr[0][e] + xv[j].y * wr[1][e]
                         + xv[j].z * wr[2][e] + xv[j].w * wr[3][e];
    }

    const bool b0 = lane & 1, b1 = lane & 2, b2 = lane & 4;
    const int elane = ((lane & 1) << 2) | (lane & 2) | ((lane >> 2) & 1);

    #pragma unroll
    for (int j = 0; j < 4; ++j) {
        float* A = a[j];
        #pragma unroll
        for (int k = 0; k < 4; ++k) {
            float t = b0 ? A[k] : A[k + 4];
            t = __shfl_xor(t, 1);
            A[k] = (b0 ? A[k + 4] : A[k]) + t;
        }
        #pragma unroll
        for (int k = 0; k < 2; ++k) {
            float t = b1 ? A[k] : A[k + 2];
            t = __shfl_xor(t, 2);
            A[k] = (b1 ? A[k + 2] : A[k]) + t;
        }
        {
            float t = b2 ? A[0] : A[1];
            t = __shfl_xor(t, 4);
            A[0] = (b2 ? A[1] : A[0]) + t;
        }
        float v = A[0];
        v += __shfl_xor(v, 8); v += __shfl_xor(v, 16); v += __shfl_xor(v, 32);
        float m = v; int mi = elane;
        #pragma unroll
        for (int off = 1; off <= 4; off <<= 1) {
            float om = __shfl_xor(m, off);
            int   oi = __shfl_xor(mi, off);
            if (om > m || (om == m && oi < mi)) { m = om; mi = oi; }
        }
        float s = expf(v - m);
        s += __shfl_xor(s, 1); s += __shfl_xor(s, 2); s += __shfl_xor(s, 4);
        if (lane == 0) {
            eid[tbase + j]  = mi;
            gate[tbase + j] = 1.0f / s;
        }
    }
}

// ---------------------------------------------------------------------------
// Kernel 2: capacity scan, 1024 threads, serial depth 8.
// ---------------------------------------------------------------------------
#define SCAN_T 1024
#define STPT 8
__global__ __launch_bounds__(1024) void scan_kernel(
    const int* __restrict__ eid, float* __restrict__ gate,
    int* __restrict__ perm) {
    __shared__ int cnt[SCAN_T][E];     // 32 KB
    __shared__ int part[E][32];
    const int tid = threadIdx.x;

    for (int i = tid; i < E * CAP; i += SCAN_T) perm[i] = -1;

    const int t0 = tid * STPT;
    int ei[STPT];
    #pragma unroll
    for (int i = 0; i < STPT; ++i) ei[i] = eid[t0 + i];

    int c[E];
    #pragma unroll
    for (int e = 0; e < E; ++e) c[e] = 0;
    #pragma unroll
    for (int i = 0; i < STPT; ++i)
        #pragma unroll
        for (int e = 0; e < E; ++e) c[e] += (ei[i] == e);
    #pragma unroll
    for (int e = 0; e < E; ++e) cnt[tid][e] = c[e];
    __syncthreads();

    if (tid < 256) {                       // 8 experts x 32 groups of 32
        const int e = tid >> 5, g = tid & 31;
        int s = 0;
        for (int i = g * 32; i < g * 32 + 32; ++i) s += cnt[i][e];
        part[e][g] = s;
    }
    __syncthreads();
    if (tid < E) {
        int run = 0;
        #pragma unroll
        for (int g = 0; g < 32; ++g) { int v = part[tid][g]; part[tid][g] = run; run += v; }
    }
    __syncthreads();
    if (tid < 256) {                       // scatter exclusive bases back into cnt
        const int e = tid >> 5, g = tid & 31;
        int run = part[e][g];
        for (int i = g * 32; i < g * 32 + 32; ++i) { int v = cnt[i][e]; cnt[i][e] = run; run += v; }
    }
    __syncthreads();

    #pragma unroll
    for (int e = 0; e < E; ++e) c[e] = cnt[tid][e];
    #pragma unroll
    for (int i = 0; i < STPT; ++i) {
        const int t = t0 + i, e0 = ei[i];
        int pos = 0;
        #pragma unroll
        for (int k = 0; k < E; ++k) if (e0 == k) pos = c[k]++;
        if (pos < CAP) perm[e0 * CAP + pos] = t;
        else gate[t] = 0.f;               // dropped; kept tokens have gate >= 1/8
    }
}

// ---------------------------------------------------------------------------
// Kernel 3: gathered GEMM, 128x128 tile, BK=64, depth-2 ring at 64 KB LDS ->
// 2 blocks/CU (4 waves/SIMD): occupancy hides what the schedule can't.
// Per step t: STAGE(t+1) into buf p^1 at the TOP of compute(t) (4 gld16/lane
// overlap MFMAs), setprio(1) around the MFMA cluster, then one
// s_waitcnt vmcnt(0) + s_barrier (loads had a full compute phase in flight).
// WAR: p^1 was last read at t-1, sealed by the end-of-(t-1) barrier.
// Blocks [0,64): zero-dropped-rows plane (LDS-free).
// ---------------------------------------------------------------------------
__global__ __launch_bounds__(512, 4) void moe_gemm_bf(
    const u16* __restrict__ xbf, const u16* __restrict__ Wbf,
    const float* __restrict__ bias, const int* __restrict__ perm,
    const float* __restrict__ gate, float* __restrict__ out) {
    __shared__ __align__(16) u16 As[2][128 * 64];   // 2 x 16 KB
    __shared__ __align__(16) u16 Bs[2][128 * 64];   // 2 x 16 KB
    __shared__ int   perm_s[128];
    __shared__ float gate_s[128];

    const int tid = threadIdx.x;
    const int bid = blockIdx.x;

    if (bid < 64) {                 // ---- zero rows of dropped tokens ----
        const int t = bid * 128 + (tid >> 2);
        if (gate[t] == 0.f) {
            const int part = tid & 3;
            float4 z = make_float4(0.f, 0.f, 0.f, 0.f);
            float4* o = (float4*)(out + (size_t)t * H + part * 256);
            #pragma unroll
            for (int i = 0; i < 64; ++i) o[i] = z;
        }
        return;
    }

    const int idx = bid - 64;
    const int e  = idx & 7;           // expert -> XCD (W_e + its tokens on one L2)
    const int mb = (idx >> 3) & 7;    // slot block (128 slots)
    const int fb = idx >> 6;          // feature block (128 features)

    if (tid < 128) {
        const int t = perm[e * CAP + mb * 128 + tid];
        perm_s[tid] = t;
        gate_s[tid] = (t >= 0) ? gate[t] : 0.f;
    }
    __syncthreads();

    const int lane = tid & 63;
    const int wv = tid >> 6;          // 0..7
    const int wm = wv >> 2;           // 0..1 : 64-row half
    const int wn = wv & 3;            // 0..3 : 32-col quarter
    const int l16 = lane & 15, quad = lane >> 4;

    // staging: wave wv covers rows [wv*16, wv*16+16), 8 rows per q-step.
    // LDS[row][c] = G[row][c ^ (row&7)] via pre-swizzled global chunk.
    const int rl  = lane >> 3;        // row within 8-row group
    const int cch = lane & 7;
    const int gch = cch ^ rl;
    const u16* ga[2];
    const u16* gb[2];
    #pragma unroll
    for (int q = 0; q < 2; ++q) {
        const int r = wv * 16 + q * 8 + rl;
        const int tA = perm_s[r];
        const int tok = tA >= 0 ? tA : 0;
        ga[q] = xbf + (size_t)tok * H + gch * 8;
        gb[q] = Wbf + (size_t)e * H * H + (size_t)(fb * 128 + r) * H + gch * 8;
    }

#define STAGE(BUF)                                                            \
    {                                                                         \
        _Pragma("unroll")                                                     \
        for (int q = 0; q < 2; ++q) {                                         \
            gld16(ga[q], &As[BUF][(wv * 16 + q * 8) * 64 + lane * 8]);        \
            gld16(gb[q], &Bs[BUF][(wv * 16 + q * 8) * 64 + lane * 8]);        \
        }                                                                     \
        _Pragma("unroll")                                                     \
        for (int q = 0; q < 2; ++q) { ga[q] += 64; gb[q] += 64; }             \
    }

    f32x4 acc[4][2] = {};

    // prologue: stage tile 0 into buf 0
    STAGE(0)
    asm volatile("s_waitcnt vmcnt(0)" ::: "memory");
    __builtin_amdgcn_sched_barrier(0);
    __builtin_amdgcn_s_barrier();
    __builtin_amdgcn_sched_barrier(0);

    int p = 0;
    #pragma unroll 1
    for (int t = 0; t < 16; ++t) {
        if (t < 15) STAGE(p ^ 1)            // overlaps with this step's MFMAs

        const u16* cA = As[p];
        const u16* cB = Bs[p];
        __builtin_amdgcn_s_setprio(1);
        #pragma unroll
        for (int kh = 0; kh < 2; ++kh) {
            bf16x8 af[4], bfr[2];
            const int cc = (kh * 4 + quad) ^ (l16 & 7);
            #pragma unroll
            for (int i = 0; i < 4; ++i)
                af[i] = *(const bf16x8*)&cA[(wm * 64 + i * 16 + l16) * 64 + cc * 8];
            #pragma unroll
            for (int i = 0; i < 2; ++i)
                bfr[i] = *(const bf16x8*)&cB[(wn * 32 + i * 16 + l16) * 64 + cc * 8];
            #pragma unroll
            for (int mi = 0; mi < 4; ++mi)
                #pragma unroll
                for (int ni = 0; ni < 2; ++ni)
                    acc[mi][ni] = __builtin_amdgcn_mfma_f32_16x16x32_bf16(
                        af[mi], bfr[ni], acc[mi][ni], 0, 0, 0);
        }
        __builtin_amdgcn_s_setprio(0);
        if (t == 15) break;

        __builtin_amdgcn_sched_barrier(0);
        asm volatile("s_waitcnt vmcnt(0)" ::: "memory");
        __builtin_amdgcn_sched_barrier(0);
        __builtin_amdgcn_s_barrier();       // single barrier per K-step
        __builtin_amdgcn_sched_barrier(0);
        p ^= 1;
    }
#undef STAGE

    // epilogue: C/D layout col=lane&15, row=quad*4+reg
    float bv[2];
    #pragma unroll
    for (int ni = 0; ni < 2; ++ni)
        bv[ni] = bias[e * H + fb * 128 + wn * 32 + ni * 16 + l16];

    #pragma unroll
    for (int mi = 0; mi < 4; ++mi) {
        #pragma unroll
        for (int r = 0; r < 4; ++r) {
            const int rowl = wm * 64 + mi * 16 + quad * 4 + r;
            const int t = perm_s[rowl];
            if (t < 0) continue;
            const float g = gate_s[rowl];
            float* orow = out + (size_t)t * H + fb * 128 + wn * 32;
            #pragma unroll
            for (int ni = 0; ni < 2; ++ni)
                orow[ni * 16 + l16] = g * (acc[mi][ni][r] + bv[ni]);
        }
    }
}

extern "C" void kernel_launch(void* const* d_in, const int* in_sizes, int n_in,
                              void* d_out, int out_size, void* d_ws, size_t ws_size,
                              hipStream_t stream) {
    const float* x    = (const float*)d_in[0];  // [T,H]
    const float* wg   = (const float*)d_in[1];  // [H,E]
    const float* W    = (const float*)d_in[2];  // [E,H,H]
    const float* bias = (const float*)d_in[3];  // [E,H]
    float* out = (float*)d_out;

    // ws: eid[T] | gate[T] | perm[E*CAP] | xbf[T*H] bf16 | Wbf[E*H*H] bf16
    int*   eid  = (int*)d_ws;
    float* gate = (float*)((char*)d_ws + (size_t)T * 4);
    int*   perm = (int*)((char*)d_ws + (size_t)T * 8);
    u16*   xbf  = (u16*)((char*)d_ws + (size_t)T * 12);
    u16*   Wbf  = xbf + (size_t)T * H;

    gatecvt_kernel<<<GATE_BLOCKS + CVT_BLOCKS, 256, 0, stream>>>(
        x, wg, W, eid, gate, xbf, Wbf);
    scan_kernel<<<1, SCAN_T, 0, stream>>>(eid, gate, perm);
    moe_gemm_bf<<<64 + 512, 512, 0, stream>>>(xbf, Wbf, bias, perm, gate, out);
}